// Round 1
// baseline (258.311 us; speedup 1.0000x reference)
//
#include <hip/hip_runtime.h>
#include <cstdint>
#include <cstddef>

typedef __bf16 bf16;
typedef __bf16 bf16x4 __attribute__((ext_vector_type(4)));
typedef __bf16 bf16x8 __attribute__((ext_vector_type(8)));
typedef float f32x4 __attribute__((ext_vector_type(4)));

static constexpr float SCALE_F = 0.35355339059327373f;  // (1024/16)^-0.25

#define AS1 __attribute__((address_space(1)))
#define AS3 __attribute__((address_space(3)))

__device__ __forceinline__ void load_lds16(const void* g, void* l) {
  __builtin_amdgcn_global_load_lds((AS1 void*)g, (AS3 void*)l, 16, 0, 0);
}

// ---------------- conversion / transpose kernels ----------------

__global__ void cvt_f32_bf16(const float* __restrict__ in, bf16* __restrict__ out, int n4) {
  int i = blockIdx.x * blockDim.x + threadIdx.x;
  if (i >= n4) return;
  float4 v = reinterpret_cast<const float4*>(in)[i];
  bf16x4 o;
  o[0] = (bf16)v.x; o[1] = (bf16)v.y; o[2] = (bf16)v.z; o[3] = (bf16)v.w;
  reinterpret_cast<bf16x4*>(out)[i] = o;
}

// inpt (B, C, T) f32  ->  X (B*T, C) bf16
__global__ void transpose_in(const float* __restrict__ inpt, bf16* __restrict__ X) {
  __shared__ float tile[32][33];
  int b = blockIdx.z;
  int t0 = blockIdx.x * 32, c0 = blockIdx.y * 32;
  int tx = threadIdx.x, ty = threadIdx.y;  // 32x8
  const float* src = inpt + ((size_t)b * 1024 + c0) * 2048 + t0;
#pragma unroll
  for (int i = 0; i < 4; ++i) tile[ty + i * 8][tx] = src[(size_t)(ty + i * 8) * 2048 + tx];
  __syncthreads();
  bf16* dst = X + ((size_t)b * 2048 + t0) * 1024 + c0;
#pragma unroll
  for (int i = 0; i < 4; ++i) dst[(size_t)(ty + i * 8) * 1024 + tx] = (bf16)tile[tx][ty + i * 8];
}

// out (B, C, T) f32 = inpt + Z(B*T, C)^T
__global__ void residual_out(const float* __restrict__ inpt, const bf16* __restrict__ Z,
                             float* __restrict__ out) {
  __shared__ float tile[32][33];
  int b = blockIdx.z;
  int t0 = blockIdx.x * 32, c0 = blockIdx.y * 32;
  int tx = threadIdx.x, ty = threadIdx.y;
  const bf16* zsrc = Z + ((size_t)b * 2048 + t0) * 1024 + c0;
#pragma unroll
  for (int i = 0; i < 4; ++i) tile[ty + i * 8][tx] = (float)zsrc[(size_t)(ty + i * 8) * 1024 + tx];
  __syncthreads();
  size_t ob = ((size_t)b * 1024 + c0) * 2048 + t0;
#pragma unroll
  for (int i = 0; i < 4; ++i) {
    size_t idx = ob + (size_t)(ty + i * 8) * 2048 + tx;
    out[idx] = inpt[idx] + tile[tx][ty + i * 8];
  }
}

// ---------------- GEMM: C[m][n] = A[m][:] . B[n][:] (+bias, epilogue by MODE) ----------------
// MODE 0: Q-proj    -> out0 = Q (B,H,T,D) bf16, val = (acc+bias)*SCALE
// MODE 1: KV-proj   -> n<1024: K (H,L,D) scaled ; n>=1024: Vt (H,D,L)
// MODE 2: out-proj  -> out0 = Z (M,1024) bf16, val = acc+bias
template <int MODE>
__global__ __launch_bounds__(256, 2) void gemm_bt(const bf16* __restrict__ A,
                                                  const bf16* __restrict__ Bw,
                                                  const float* __restrict__ bias,
                                                  bf16* __restrict__ out0,
                                                  bf16* __restrict__ out1, int M, int N, int K) {
  __shared__ __align__(16) char sA[16384];  // 128 x 64 bf16, XOR-swizzled rows
  __shared__ __align__(16) char sB[16384];
  const int tid = threadIdx.x;
  const int lane = tid & 63;
  const int wave = tid >> 6;
  const int wm = wave >> 1, wn = wave & 1;  // 2x2 waves, 64x64 each
  const int m0 = blockIdx.x * 128, n0 = blockIdx.y * 128;
  f32x4 acc[4][4] = {};

  for (int kt = 0; kt < K; kt += 64) {
#pragma unroll
    for (int j = 0; j < 4; ++j) {
      int i = tid + j * 256;
      int r = i >> 3, q = i & 7;
      int so = (q ^ (r & 7)) << 4;  // pre-swizzled source so linear LDS == swizzled layout
      load_lds16((const char*)(A + (size_t)(m0 + r) * K + kt) + so, sA + (size_t)i * 16);
      load_lds16((const char*)(Bw + (size_t)(n0 + r) * K + kt) + so, sB + (size_t)i * 16);
    }
    asm volatile("s_waitcnt vmcnt(0)" ::: "memory");
    __syncthreads();
    bf16x8 af[4][2], bfr[4][2];
#pragma unroll
    for (int mi = 0; mi < 4; ++mi)
#pragma unroll
      for (int kk = 0; kk < 2; ++kk) {
        int rr = wm * 64 + mi * 16 + (lane & 15);
        int w = kk * 64 + ((lane >> 4) << 4);
        af[mi][kk] = *(const bf16x8*)(sA + (size_t)rr * 128 + (w ^ ((rr & 7) << 4)));
        int r2 = wn * 64 + mi * 16 + (lane & 15);
        bfr[mi][kk] = *(const bf16x8*)(sB + (size_t)r2 * 128 + (w ^ ((r2 & 7) << 4)));
      }
#pragma unroll
    for (int kk = 0; kk < 2; ++kk)
#pragma unroll
      for (int mi = 0; mi < 4; ++mi)
#pragma unroll
        for (int ni = 0; ni < 4; ++ni)
          acc[mi][ni] =
              __builtin_amdgcn_mfma_f32_16x16x32_bf16(af[mi][kk], bfr[ni][kk], acc[mi][ni], 0, 0, 0);
    __syncthreads();
  }

  float bs[4];
#pragma unroll
  for (int ni = 0; ni < 4; ++ni) bs[ni] = bias[n0 + wn * 64 + ni * 16 + (lane & 15)];

#pragma unroll
  for (int mi = 0; mi < 4; ++mi)
#pragma unroll
    for (int ni = 0; ni < 4; ++ni)
#pragma unroll
      for (int j = 0; j < 4; ++j) {
        int row = wm * 64 + mi * 16 + ((lane >> 4) << 2) + j;
        int col = wn * 64 + ni * 16 + (lane & 15);
        int m = m0 + row, n = n0 + col;
        float val = acc[mi][ni][j] + bs[ni];
        if constexpr (MODE == 0) {
          val *= SCALE_F;
          int bb = m >> 11, t = m & 2047, hh = n >> 6, d = n & 63;
          out0[(((size_t)(bb * 16 + hh) * 2048 + t) << 6) + d] = (bf16)val;
        } else if constexpr (MODE == 1) {
          if (n < 1024) {
            int hh = n >> 6, d = n & 63;
            out0[(((size_t)hh * 512 + m) << 6) + d] = (bf16)(val * SCALE_F);
          } else {
            int n2 = n - 1024;
            int hh = n2 >> 6, d = n2 & 63;
            out1[(((size_t)hh * 64 + d) << 9) + m] = (bf16)val;
          }
        } else {
          out0[(size_t)m * 1024 + n] = (bf16)val;
        }
      }
}

// ---------------- attention: per (b, h, 64-row t tile); all 512 keys in LDS ----------------
// LDS map (132352 B):
//   phase 1/2: K [0,65536) 512x64 bf16 swz ; Q [65536,73728) 64x64 bf16 swz
//   phase 3/4: S [0,132096) 64 rows x 516 f32
//   phase 5/6: P [0,65536) 64x512 bf16 swz ; Vt [66560,132096) 64x512 bf16 swz ; inv [132096,+256)
__global__ __launch_bounds__(512, 1) void attn_kernel(const bf16* __restrict__ Q,
                                                      const bf16* __restrict__ Kw,
                                                      const bf16* __restrict__ Vt,
                                                      bf16* __restrict__ Y) {
  __shared__ __align__(16) char lds[132352];
  const int tid = threadIdx.x;
  const int lane = tid & 63;
  const int wave = tid >> 6;
  const int t0 = blockIdx.x * 64;
  const int bh = blockIdx.y;
  const int b = bh >> 4, h = bh & 15;

  const bf16* Kh = Kw + (size_t)h * 512 * 64;
#pragma unroll
  for (int j = 0; j < 8; ++j) {
    int i = tid + j * 512;
    int r = i >> 3, q = i & 7;
    load_lds16((const char*)(Kh + (size_t)r * 64) + ((q ^ (r & 7)) << 4), lds + (size_t)i * 16);
  }
  {
    const bf16* Qh = Q + ((size_t)(b * 16 + h) * 2048 + t0) * 64;
    int r = tid >> 3, q = tid & 7;
    load_lds16((const char*)(Qh + (size_t)r * 64) + ((q ^ (r & 7)) << 4),
               lds + 65536 + (size_t)tid * 16);
  }
  asm volatile("s_waitcnt vmcnt(0)" ::: "memory");
  __syncthreads();

  // S = Q K^T ; wave w owns j in [64w, 64w+64)
  f32x4 acc[4][4] = {};
  {
    bf16x8 af[4][2], bfr[4][2];
#pragma unroll
    for (int mi = 0; mi < 4; ++mi)
#pragma unroll
      for (int kk = 0; kk < 2; ++kk) {
        int rr = mi * 16 + (lane & 15);
        int w = kk * 64 + ((lane >> 4) << 4);
        af[mi][kk] = *(const bf16x8*)(lds + 65536 + (size_t)rr * 128 + (w ^ ((rr & 7) << 4)));
        int jj = wave * 64 + mi * 16 + (lane & 15);
        bfr[mi][kk] = *(const bf16x8*)(lds + (size_t)jj * 128 + (w ^ ((jj & 7) << 4)));
      }
#pragma unroll
    for (int kk = 0; kk < 2; ++kk)
#pragma unroll
      for (int mi = 0; mi < 4; ++mi)
#pragma unroll
        for (int ni = 0; ni < 4; ++ni)
          acc[mi][ni] =
              __builtin_amdgcn_mfma_f32_16x16x32_bf16(af[mi][kk], bfr[ni][kk], acc[mi][ni], 0, 0, 0);
  }
  __syncthreads();  // done reading K/Q LDS

#pragma unroll
  for (int mi = 0; mi < 4; ++mi)
#pragma unroll
    for (int ni = 0; ni < 4; ++ni)
#pragma unroll
      for (int j = 0; j < 4; ++j) {
        int row = mi * 16 + ((lane >> 4) << 2) + j;
        int col = wave * 64 + ni * 16 + (lane & 15);
        *(float*)(lds + ((size_t)row * 516 + col) * 4) = acc[mi][ni][j];
      }
  __syncthreads();

  // softmax: 8 threads per row, 64 f32 each
  const bf16* Vh = Vt + (size_t)h * 64 * 512;
  {
    int srow = tid >> 3, sub = tid & 7;
    const char* sbase = lds + ((size_t)srow * 516 + sub * 64) * 4;
    f32x4 v4[16];
#pragma unroll
    for (int i = 0; i < 16; ++i) v4[i] = *(const f32x4*)(sbase + i * 16);
    __syncthreads();  // S fully consumed; P / Vt regions free

    // issue Vt staging now; HBM latency hides under exp/sum below (T14-lite)
#pragma unroll
    for (int j = 0; j < 8; ++j) {
      int i = tid + j * 512;
      int r = i >> 6, q = i & 63;
      load_lds16((const char*)(Vh + (size_t)r * 512) + ((q ^ (r & 7)) << 4),
                 lds + 66560 + (size_t)i * 16);
    }

    float mx = -3e38f;
#pragma unroll
    for (int i = 0; i < 16; ++i)
      mx = fmaxf(mx, fmaxf(fmaxf(v4[i][0], v4[i][1]), fmaxf(v4[i][2], v4[i][3])));
    mx = fmaxf(mx, __shfl_xor(mx, 1));
    mx = fmaxf(mx, __shfl_xor(mx, 2));
    mx = fmaxf(mx, __shfl_xor(mx, 4));

    float s = 0.f;
    bf16x8 pk[8];
#pragma unroll
    for (int c = 0; c < 8; ++c)
#pragma unroll
      for (int e = 0; e < 8; ++e) {
        float p = __expf(v4[2 * c + (e >> 2)][e & 3] - mx);
        s += p;
        pk[c][e] = (bf16)p;
      }
    s += __shfl_xor(s, 1);
    s += __shfl_xor(s, 2);
    s += __shfl_xor(s, 4);

#pragma unroll
    for (int c = 0; c < 8; ++c) {
      int wbyte = (sub * 128 + c * 16) ^ ((srow & 7) << 4);
      *(bf16x8*)(lds + (size_t)srow * 1024 + wbyte) = pk[c];  // unnormalized P
    }
    if (sub == 0) *(float*)(lds + 132096 + (size_t)srow * 4) = 1.0f / s;
  }
  asm volatile("s_waitcnt vmcnt(0)" ::: "memory");
  __syncthreads();

  // O = P Vt^T ; wave w owns frags {2w, 2w+1} of the 4x4 (16-row x 16-col) grid
  {
    int f0 = wave * 2;
    int mi = f0 >> 2;
    int nb = f0 & 3;
    f32x4 o0 = {0.f, 0.f, 0.f, 0.f}, o1 = {0.f, 0.f, 0.f, 0.f};
#pragma unroll
    for (int kk = 0; kk < 16; ++kk) {
      int rr = mi * 16 + (lane & 15);
      int w = kk * 64 + ((lane >> 4) << 4);
      bf16x8 ap = *(const bf16x8*)(lds + (size_t)rr * 1024 + (w ^ ((rr & 7) << 4)));
      int d0 = nb * 16 + (lane & 15);
      bf16x8 bv0 = *(const bf16x8*)(lds + 66560 + (size_t)d0 * 1024 + (w ^ ((d0 & 7) << 4)));
      o0 = __builtin_amdgcn_mfma_f32_16x16x32_bf16(ap, bv0, o0, 0, 0, 0);
      int d1 = (nb + 1) * 16 + (lane & 15);
      bf16x8 bv1 = *(const bf16x8*)(lds + 66560 + (size_t)d1 * 1024 + (w ^ ((d1 & 7) << 4)));
      o1 = __builtin_amdgcn_mfma_f32_16x16x32_bf16(ap, bv1, o1, 0, 0, 0);
    }
#pragma unroll
    for (int j = 0; j < 4; ++j) {
      int row = mi * 16 + ((lane >> 4) << 2) + j;
      float inv = *(const float*)(lds + 132096 + (size_t)row * 4);
      int t = t0 + row;
      int c0 = nb * 16 + (lane & 15);
      Y[((size_t)b * 2048 + t) * 1024 + h * 64 + c0] = (bf16)(o0[j] * inv);
      int c1 = (nb + 1) * 16 + (lane & 15);
      Y[((size_t)b * 2048 + t) * 1024 + h * 64 + c1] = (bf16)(o1[j] * inv);
    }
  }
}

// ---------------- launch ----------------

extern "C" void kernel_launch(void* const* d_in, const int* in_sizes, int n_in, void* d_out,
                              int out_size, void* d_ws, size_t ws_size, hipStream_t stream) {
  const float* inpt = (const float*)d_in[0];
  const float* aux = (const float*)d_in[1];
  const float* q_w = (const float*)d_in[2];
  const float* q_b = (const float*)d_in[3];
  const float* kv_w = (const float*)d_in[4];
  const float* kv_b = (const float*)d_in[5];
  const float* out_w = (const float*)d_in[6];
  const float* out_b = (const float*)d_in[7];
  float* out = (float*)d_out;
  char* ws = (char*)d_ws;
  // ws layout (43 MB total, with reuse):
  bf16* X = (bf16*)(ws + 0);                        // 16MB: X bf16 ; reused as attn-out Y
  bf16* QZ = (bf16*)(ws + (16u << 20));             // 16MB: Q (B,H,T,D) ; reused as Z
  bf16* qwb = (bf16*)(ws + (32u << 20));            // 2MB
  bf16* kvwb = (bf16*)(ws + (34u << 20));           // 4MB
  bf16* owb = (bf16*)(ws + (38u << 20));            // 2MB
  bf16* auxb = (bf16*)(ws + (40u << 20));           // 1MB
  bf16* Kws = (bf16*)(ws + (41u << 20));            // 1MB (H,L,D)
  bf16* Vtw = (bf16*)(ws + (42u << 20));            // 1MB (H,D,L)

  cvt_f32_bf16<<<1024, 256, 0, stream>>>(q_w, qwb, 1024 * 1024 / 4);
  cvt_f32_bf16<<<2048, 256, 0, stream>>>(kv_w, kvwb, 2048 * 1024 / 4);
  cvt_f32_bf16<<<1024, 256, 0, stream>>>(out_w, owb, 1024 * 1024 / 4);
  cvt_f32_bf16<<<512, 256, 0, stream>>>(aux, auxb, 512 * 1024 / 4);
  transpose_in<<<dim3(64, 32, 4), dim3(32, 8), 0, stream>>>(inpt, X);

  gemm_bt<1><<<dim3(4, 16), 256, 0, stream>>>(auxb, kvwb, kv_b, Kws, Vtw, 512, 2048, 1024);
  gemm_bt<0><<<dim3(64, 8), 256, 0, stream>>>(X, qwb, q_b, QZ, nullptr, 8192, 1024, 1024);
  attn_kernel<<<dim3(32, 64), 512, 0, stream>>>(QZ, Kws, Vtw, X /* Y reuses X */);
  gemm_bt<2><<<dim3(64, 8), 256, 0, stream>>>(X, owb, out_b, QZ /* Z reuses Q */, nullptr, 8192,
                                              1024, 1024);
  residual_out<<<dim3(64, 32, 4), dim3(32, 8), 0, stream>>>(inpt, QZ, out);
}

// Round 2
// 238.293 us; speedup vs baseline: 1.0840x; 1.0840x over previous
//
#include <hip/hip_runtime.h>
#include <cstdint>
#include <cstddef>

typedef __bf16 bf16;
typedef __bf16 bf16x4 __attribute__((ext_vector_type(4)));
typedef __bf16 bf16x8 __attribute__((ext_vector_type(8)));
typedef float f32x4 __attribute__((ext_vector_type(4)));

static constexpr float SCALE_F = 0.35355339059327373f;  // (1024/16)^-0.25

#define AS1 __attribute__((address_space(1)))
#define AS3 __attribute__((address_space(3)))

__device__ __forceinline__ void load_lds16(const void* g, void* l) {
  __builtin_amdgcn_global_load_lds((AS1 void*)g, (AS3 void*)l, 16, 0, 0);
}

// ---------------- conversion / transpose kernels ----------------

__global__ void cvt_f32_bf16(const float* __restrict__ in, bf16* __restrict__ out, int n4) {
  int i = blockIdx.x * blockDim.x + threadIdx.x;
  if (i >= n4) return;
  float4 v = reinterpret_cast<const float4*>(in)[i];
  bf16x4 o;
  o[0] = (bf16)v.x; o[1] = (bf16)v.y; o[2] = (bf16)v.z; o[3] = (bf16)v.w;
  reinterpret_cast<bf16x4*>(out)[i] = o;
}

// inpt (B, C, T) f32  ->  X (B*T, C) bf16
__global__ void transpose_in(const float* __restrict__ inpt, bf16* __restrict__ X) {
  __shared__ float tile[32][33];
  int b = blockIdx.z;
  int t0 = blockIdx.x * 32, c0 = blockIdx.y * 32;
  int tx = threadIdx.x, ty = threadIdx.y;  // 32x8
  const float* src = inpt + ((size_t)b * 1024 + c0) * 2048 + t0;
#pragma unroll
  for (int i = 0; i < 4; ++i) tile[ty + i * 8][tx] = src[(size_t)(ty + i * 8) * 2048 + tx];
  __syncthreads();
  bf16* dst = X + ((size_t)b * 2048 + t0) * 1024 + c0;
#pragma unroll
  for (int i = 0; i < 4; ++i) dst[(size_t)(ty + i * 8) * 1024 + tx] = (bf16)tile[tx][ty + i * 8];
}

// out (B, C, T) f32 = inpt + Z(B*T, C)^T
__global__ void residual_out(const float* __restrict__ inpt, const bf16* __restrict__ Z,
                             float* __restrict__ out) {
  __shared__ float tile[32][33];
  int b = blockIdx.z;
  int t0 = blockIdx.x * 32, c0 = blockIdx.y * 32;
  int tx = threadIdx.x, ty = threadIdx.y;
  const bf16* zsrc = Z + ((size_t)b * 2048 + t0) * 1024 + c0;
#pragma unroll
  for (int i = 0; i < 4; ++i) tile[ty + i * 8][tx] = (float)zsrc[(size_t)(ty + i * 8) * 1024 + tx];
  __syncthreads();
  size_t ob = ((size_t)b * 1024 + c0) * 2048 + t0;
#pragma unroll
  for (int i = 0; i < 4; ++i) {
    size_t idx = ob + (size_t)(ty + i * 8) * 2048 + tx;
    out[idx] = inpt[idx] + tile[tx][ty + i * 8];
  }
}

// ---------------- GEMM: C[m][n] = A[m][:] . B[n][:] (+bias, epilogue by MODE) ----------------
// MODE 0: Q-proj    -> out0 = Q (B,H,T,D) bf16, val = (acc+bias)*SCALE
// MODE 1: KV-proj   -> n<1024: K (H,L,D) scaled ; n>=1024: Vt (H,D,L)
// MODE 2: out-proj  -> out0 = Z (M,1024) bf16, val = acc+bias
template <int MODE>
__global__ __launch_bounds__(256, 2) void gemm_bt(const bf16* __restrict__ A,
                                                  const bf16* __restrict__ Bw,
                                                  const float* __restrict__ bias,
                                                  bf16* __restrict__ out0,
                                                  bf16* __restrict__ out1, int M, int N, int K) {
  __shared__ __align__(16) char sA[16384];  // 128 x 64 bf16, XOR-swizzled rows
  __shared__ __align__(16) char sB[16384];
  const int tid = threadIdx.x;
  const int lane = tid & 63;
  const int wave = tid >> 6;
  const int wm = wave >> 1, wn = wave & 1;  // 2x2 waves, 64x64 each
  const int m0 = blockIdx.x * 128, n0 = blockIdx.y * 128;
  f32x4 acc[4][4] = {};

  for (int kt = 0; kt < K; kt += 64) {
#pragma unroll
    for (int j = 0; j < 4; ++j) {
      int i = tid + j * 256;
      int r = i >> 3, q = i & 7;
      int so = (q ^ (r & 7)) << 4;  // pre-swizzled source so linear LDS == swizzled layout
      load_lds16((const char*)(A + (size_t)(m0 + r) * K + kt) + so, sA + (size_t)i * 16);
      load_lds16((const char*)(Bw + (size_t)(n0 + r) * K + kt) + so, sB + (size_t)i * 16);
    }
    asm volatile("s_waitcnt vmcnt(0)" ::: "memory");
    __syncthreads();
    bf16x8 af[4][2], bfr[4][2];
#pragma unroll
    for (int mi = 0; mi < 4; ++mi)
#pragma unroll
      for (int kk = 0; kk < 2; ++kk) {
        int rr = wm * 64 + mi * 16 + (lane & 15);
        int w = kk * 64 + ((lane >> 4) << 4);
        af[mi][kk] = *(const bf16x8*)(sA + (size_t)rr * 128 + (w ^ ((rr & 7) << 4)));
        int r2 = wn * 64 + mi * 16 + (lane & 15);
        bfr[mi][kk] = *(const bf16x8*)(sB + (size_t)r2 * 128 + (w ^ ((r2 & 7) << 4)));
      }
#pragma unroll
    for (int kk = 0; kk < 2; ++kk)
#pragma unroll
      for (int mi = 0; mi < 4; ++mi)
#pragma unroll
        for (int ni = 0; ni < 4; ++ni)
          acc[mi][ni] =
              __builtin_amdgcn_mfma_f32_16x16x32_bf16(af[mi][kk], bfr[ni][kk], acc[mi][ni], 0, 0, 0);
    __syncthreads();
  }

  float bs[4];
#pragma unroll
  for (int ni = 0; ni < 4; ++ni) bs[ni] = bias[n0 + wn * 64 + ni * 16 + (lane & 15)];

#pragma unroll
  for (int mi = 0; mi < 4; ++mi)
#pragma unroll
    for (int ni = 0; ni < 4; ++ni)
#pragma unroll
      for (int j = 0; j < 4; ++j) {
        int row = wm * 64 + mi * 16 + ((lane >> 4) << 2) + j;
        int col = wn * 64 + ni * 16 + (lane & 15);
        int m = m0 + row, n = n0 + col;
        float val = acc[mi][ni][j] + bs[ni];
        if constexpr (MODE == 0) {
          val *= SCALE_F;
          int bb = m >> 11, t = m & 2047, hh = n >> 6, d = n & 63;
          out0[(((size_t)(bb * 16 + hh) * 2048 + t) << 6) + d] = (bf16)val;
        } else if constexpr (MODE == 1) {
          if (n < 1024) {
            int hh = n >> 6, d = n & 63;
            out0[(((size_t)hh * 512 + m) << 6) + d] = (bf16)(val * SCALE_F);
          } else {
            int n2 = n - 1024;
            int hh = n2 >> 6, d = n2 & 63;
            out1[(((size_t)hh * 64 + d) << 9) + m] = (bf16)val;
          }
        } else {
          out0[(size_t)m * 1024 + n] = (bf16)val;
        }
      }
}

// ---------------- attention v2 ----------------
// One block = (b, h, 64 q-rows), 512 threads (8 waves).
// LDS 73728 B: P/O region [0,65536) ; Q region [65536,73728).
// Swapped QK^T (S^T: col=q), constant-shift softmax (M=16, exact: per-row
// constant cancels in softmax), row sums via mfma(ones, P), K/Vt fragments
// straight from global (L2-resident, 64KB/head). 2 blocks/CU.
__global__ __launch_bounds__(512, 4) void attn_kernel(const bf16* __restrict__ Q,
                                                      const bf16* __restrict__ Kw,
                                                      const bf16* __restrict__ Vt,
                                                      bf16* __restrict__ Y) {
  __shared__ __align__(16) char lds[73728];
  const int tid = threadIdx.x;
  const int lane = tid & 63;
  const int wv = tid >> 6;
  const int g = lane >> 4;   // lane quarter-group 0..3
  const int lr = lane & 15;  // row/col within 16
  const int t0 = blockIdx.x * 64;
  const int bh = blockIdx.y;
  const int b = bh >> 4, h = bh & 15;

  // stage Q tile (64 rows x 128B) with pre-swizzled source -> swizzled LDS
  {
    const bf16* Qh = Q + ((size_t)(b * 16 + h) * 2048 + t0) * 64;
    int r = tid >> 3, c = tid & 7;
    load_lds16((const char*)Qh + r * 128 + ((c * 16) ^ ((r & 7) << 4)),
               lds + 65536 + (size_t)tid * 16);
  }
  asm volatile("s_waitcnt vmcnt(0)" ::: "memory");
  __syncthreads();

  // QK^T swapped: acc[mi][ni] = S^T frag; key = 64*wv + 16*mi + 4*g + j, q = 16*ni + lr
  f32x4 acc[4][4] = {};
  const bf16* Kh = Kw + (size_t)h * 512 * 64;
#pragma unroll
  for (int kk = 0; kk < 2; ++kk) {
    bf16x8 ka[4], qb[4];
#pragma unroll
    for (int mi = 0; mi < 4; ++mi) {
      int key = wv * 64 + mi * 16 + lr;
      ka[mi] = *(const bf16x8*)((const char*)Kh + (size_t)key * 128 + kk * 64 + g * 16);
    }
#pragma unroll
    for (int ni = 0; ni < 4; ++ni) {
      int q = ni * 16 + lr;
      qb[ni] = *(const bf16x8*)(lds + 65536 + (size_t)q * 128 +
                                ((kk * 64 + g * 16) ^ ((q & 7) << 4)));
    }
#pragma unroll
    for (int mi = 0; mi < 4; ++mi)
#pragma unroll
      for (int ni = 0; ni < 4; ++ni)
        acc[mi][ni] =
            __builtin_amdgcn_mfma_f32_16x16x32_bf16(ka[mi], qb[ni], acc[mi][ni], 0, 0, 0);
  }

  // P = exp(S - 16) -> bf16, packed b64 writes into P[q][key] (row 1024B, quad-swizzled)
#pragma unroll
  for (int mi = 0; mi < 4; ++mi)
#pragma unroll
    for (int ni = 0; ni < 4; ++ni) {
      int q = ni * 16 + lr;
      bf16x4 w;
#pragma unroll
      for (int j = 0; j < 4; ++j) w[j] = (bf16)__expf(acc[mi][ni][j] - 16.0f);
      int byt = (wv * 128 + mi * 32 + g * 8) ^ ((q & 7) << 4);
      *(bf16x4*)(lds + (size_t)q * 1024 + byt) = w;
    }
  __syncthreads();

  // PV: wave -> d-block mi_o = wv>>1 ; q-blocks n0, n0+1. A = Vt rows (global), B = P rows (LDS).
  const int mi_o = wv >> 1;
  const int n0 = (wv & 1) * 2;
  const bf16* Vh = Vt + (size_t)h * 64 * 512;
  const bf16 one = (bf16)1.0f;
  const bf16x8 ones = {one, one, one, one, one, one, one, one};
  f32x4 o0 = {}, o1 = {}, s0 = {}, s1 = {};
  const int d = mi_o * 16 + lr;
  const int q0 = n0 * 16 + lr, q1 = q0 + 16;
#pragma unroll
  for (int kk = 0; kk < 16; ++kk) {
    bf16x8 va = *(const bf16x8*)((const char*)Vh + (size_t)d * 1024 + kk * 64 + g * 16);
    bf16x8 p0 = *(const bf16x8*)(lds + (size_t)q0 * 1024 + ((kk * 64 + g * 16) ^ ((q0 & 7) << 4)));
    bf16x8 p1 = *(const bf16x8*)(lds + (size_t)q1 * 1024 + ((kk * 64 + g * 16) ^ ((q1 & 7) << 4)));
    o0 = __builtin_amdgcn_mfma_f32_16x16x32_bf16(va, p0, o0, 0, 0, 0);
    o1 = __builtin_amdgcn_mfma_f32_16x16x32_bf16(va, p1, o1, 0, 0, 0);
    s0 = __builtin_amdgcn_mfma_f32_16x16x32_bf16(ones, p0, s0, 0, 0, 0);
    s1 = __builtin_amdgcn_mfma_f32_16x16x32_bf16(ones, p1, s1, 0, 0, 0);
  }
  __syncthreads();  // all P reads complete; P region reusable for O

  // normalize, write O^T transposed to LDS as O[q][d] f32 (row 256B, quad-swizzled)
  {
    float i0 = 1.0f / s0[0], i1 = 1.0f / s1[0];
    int byt = mi_o * 64 + g * 16;
    f32x4 w0, w1;
#pragma unroll
    for (int j = 0; j < 4; ++j) {
      w0[j] = o0[j] * i0;
      w1[j] = o1[j] * i1;
    }
    *(f32x4*)(lds + (size_t)q0 * 256 + (byt ^ ((q0 & 7) << 4))) = w0;
    *(f32x4*)(lds + (size_t)q1 * 256 + (byt ^ ((q1 & 7) << 4))) = w1;
  }
  __syncthreads();

  // coalesced store: thread -> (q = tid>>3, 8 d's)
  {
    int q = tid >> 3, sub = tid & 7;
    int base = sub * 32;
    f32x4 a = *(const f32x4*)(lds + (size_t)q * 256 + (base ^ ((q & 7) << 4)));
    f32x4 c = *(const f32x4*)(lds + (size_t)q * 256 + ((base + 16) ^ ((q & 7) << 4)));
    bf16x8 w;
#pragma unroll
    for (int j = 0; j < 4; ++j) {
      w[j] = (bf16)a[j];
      w[4 + j] = (bf16)c[j];
    }
    *(bf16x8*)((char*)Y + (((size_t)(b * 2048 + t0 + q) * 1024 + h * 64 + sub * 8) * 2)) = w;
  }
}

// ---------------- launch ----------------

extern "C" void kernel_launch(void* const* d_in, const int* in_sizes, int n_in, void* d_out,
                              int out_size, void* d_ws, size_t ws_size, hipStream_t stream) {
  const float* inpt = (const float*)d_in[0];
  const float* aux = (const float*)d_in[1];
  const float* q_w = (const float*)d_in[2];
  const float* q_b = (const float*)d_in[3];
  const float* kv_w = (const float*)d_in[4];
  const float* kv_b = (const float*)d_in[5];
  const float* out_w = (const float*)d_in[6];
  const float* out_b = (const float*)d_in[7];
  float* out = (float*)d_out;
  char* ws = (char*)d_ws;
  // ws layout (43 MB total, with reuse):
  bf16* X = (bf16*)(ws + 0);                        // 16MB: X bf16 ; reused as attn-out Y
  bf16* QZ = (bf16*)(ws + (16u << 20));             // 16MB: Q (B,H,T,D) ; reused as Z
  bf16* qwb = (bf16*)(ws + (32u << 20));            // 2MB
  bf16* kvwb = (bf16*)(ws + (34u << 20));           // 4MB
  bf16* owb = (bf16*)(ws + (38u << 20));            // 2MB
  bf16* auxb = (bf16*)(ws + (40u << 20));           // 1MB
  bf16* Kws = (bf16*)(ws + (41u << 20));            // 1MB (H,L,D)
  bf16* Vtw = (bf16*)(ws + (42u << 20));            // 1MB (H,D,L)

  cvt_f32_bf16<<<1024, 256, 0, stream>>>(q_w, qwb, 1024 * 1024 / 4);
  cvt_f32_bf16<<<2048, 256, 0, stream>>>(kv_w, kvwb, 2048 * 1024 / 4);
  cvt_f32_bf16<<<1024, 256, 0, stream>>>(out_w, owb, 1024 * 1024 / 4);
  cvt_f32_bf16<<<512, 256, 0, stream>>>(aux, auxb, 512 * 1024 / 4);
  transpose_in<<<dim3(64, 32, 4), dim3(32, 8), 0, stream>>>(inpt, X);

  gemm_bt<1><<<dim3(4, 16), 256, 0, stream>>>(auxb, kvwb, kv_b, Kws, Vtw, 512, 2048, 1024);
  gemm_bt<0><<<dim3(64, 8), 256, 0, stream>>>(X, qwb, q_b, QZ, nullptr, 8192, 1024, 1024);
  attn_kernel<<<dim3(32, 64), 512, 0, stream>>>(QZ, Kws, Vtw, X /* Y reuses X */);
  gemm_bt<2><<<dim3(64, 8), 256, 0, stream>>>(X, owb, out_b, QZ /* Z reuses Q */, nullptr, 8192,
                                              1024, 1024);
  residual_out<<<dim3(64, 32, 4), dim3(32, 8), 0, stream>>>(inpt, QZ, out);
}

// Round 3
// 222.688 us; speedup vs baseline: 1.1600x; 1.0701x over previous
//
#include <hip/hip_runtime.h>
#include <cstdint>
#include <cstddef>

typedef __bf16 bf16;
typedef __bf16 bf16x4 __attribute__((ext_vector_type(4)));
typedef __bf16 bf16x8 __attribute__((ext_vector_type(8)));
typedef float f32x4 __attribute__((ext_vector_type(4)));

static constexpr float SCALE_F = 0.35355339059327373f;  // (1024/16)^-0.25

#define AS1 __attribute__((address_space(1)))
#define AS3 __attribute__((address_space(3)))

__device__ __forceinline__ void load_lds16(const void* g, void* l) {
  __builtin_amdgcn_global_load_lds((AS1 void*)g, (AS3 void*)l, 16, 0, 0);
}

// ---------------- fused f32->bf16 conversion (4 buffers, one launch) ----------------

__global__ void cvt_all(const float* __restrict__ a, bf16* __restrict__ oa,
                        const float* __restrict__ b, bf16* __restrict__ ob,
                        const float* __restrict__ c, bf16* __restrict__ oc,
                        const float* __restrict__ d, bf16* __restrict__ od) {
  int i = blockIdx.x * blockDim.x + threadIdx.x;  // float4 index
  const float* src;
  bf16* dst;
  int off;
  if (i < 262144) { src = a; dst = oa; off = i; }
  else if (i < 786432) { src = b; dst = ob; off = i - 262144; }
  else if (i < 1048576) { src = c; dst = oc; off = i - 786432; }
  else { src = d; dst = od; off = i - 1048576; }
  float4 v = reinterpret_cast<const float4*>(src)[off];
  bf16x4 o;
  o[0] = (bf16)v.x; o[1] = (bf16)v.y; o[2] = (bf16)v.z; o[3] = (bf16)v.w;
  reinterpret_cast<bf16x4*>(dst)[off] = o;
}

// inpt (B, C, T) f32  ->  X (B*T, C) bf16
__global__ void transpose_in(const float* __restrict__ inpt, bf16* __restrict__ X) {
  __shared__ float tile[32][33];
  int b = blockIdx.z;
  int t0 = blockIdx.x * 32, c0 = blockIdx.y * 32;
  int tx = threadIdx.x, ty = threadIdx.y;  // 32x8
  const float* src = inpt + ((size_t)b * 1024 + c0) * 2048 + t0;
#pragma unroll
  for (int i = 0; i < 4; ++i) tile[ty + i * 8][tx] = src[(size_t)(ty + i * 8) * 2048 + tx];
  __syncthreads();
  bf16* dst = X + ((size_t)b * 2048 + t0) * 1024 + c0;
#pragma unroll
  for (int i = 0; i < 4; ++i) dst[(size_t)(ty + i * 8) * 1024 + tx] = (bf16)tile[tx][ty + i * 8];
}

// out (B, C, T) f32 = inpt + Z(B*T, C)^T
__global__ void residual_out(const float* __restrict__ inpt, const bf16* __restrict__ Z,
                             float* __restrict__ out) {
  __shared__ float tile[32][33];
  int b = blockIdx.z;
  int t0 = blockIdx.x * 32, c0 = blockIdx.y * 32;
  int tx = threadIdx.x, ty = threadIdx.y;
  const bf16* zsrc = Z + ((size_t)b * 2048 + t0) * 1024 + c0;
#pragma unroll
  for (int i = 0; i < 4; ++i) tile[ty + i * 8][tx] = (float)zsrc[(size_t)(ty + i * 8) * 1024 + tx];
  __syncthreads();
  size_t ob = ((size_t)b * 1024 + c0) * 2048 + t0;
#pragma unroll
  for (int i = 0; i < 4; ++i) {
    size_t idx = ob + (size_t)(ty + i * 8) * 2048 + tx;
    out[idx] = inpt[idx] + tile[tx][ty + i * 8];
  }
}

// ---------------- GEMM core macro-structure (128x128 tile, K=1024, B^T weights) ----------------
// Shared K-loop; epilogue differs per call site.

// Fused Q-proj + KV-proj: blocks [0,512) do Q (M=8192,N=1024), blocks [512,576) do KV (M=512,N=2048).
__global__ __launch_bounds__(256, 2) void gemm_qkv(
    const bf16* __restrict__ X, const bf16* __restrict__ qwb, const float* __restrict__ q_b,
    bf16* __restrict__ Qout, const bf16* __restrict__ auxb, const bf16* __restrict__ kvwb,
    const float* __restrict__ kv_b, bf16* __restrict__ Kout, bf16* __restrict__ Vout) {
  __shared__ __align__(16) char sA[16384];  // 128 x 64 bf16, XOR-swizzled rows
  __shared__ __align__(16) char sB[16384];
  const int tid = threadIdx.x;
  const int lane = tid & 63;
  const int wave = tid >> 6;
  const int wm = wave >> 1, wn = wave & 1;
  const int bid = blockIdx.x;
  const bool isQ = bid < 512;
  const bf16 *A, *Bw;
  const float* bias;
  int m0, n0;
  if (isQ) {
    A = X; Bw = qwb; bias = q_b;
    m0 = (bid >> 3) * 128; n0 = (bid & 7) * 128;
  } else {
    int b2 = bid - 512;
    A = auxb; Bw = kvwb; bias = kv_b;
    m0 = (b2 & 3) * 128; n0 = (b2 >> 2) * 128;
  }
  f32x4 acc[4][4] = {};

  for (int kt = 0; kt < 1024; kt += 64) {
#pragma unroll
    for (int j = 0; j < 4; ++j) {
      int i = tid + j * 256;
      int r = i >> 3, q = i & 7;
      int so = (q ^ (r & 7)) << 4;
      load_lds16((const char*)(A + (size_t)(m0 + r) * 1024 + kt) + so, sA + (size_t)i * 16);
      load_lds16((const char*)(Bw + (size_t)(n0 + r) * 1024 + kt) + so, sB + (size_t)i * 16);
    }
    asm volatile("s_waitcnt vmcnt(0)" ::: "memory");
    __syncthreads();
    bf16x8 af[4][2], bfr[4][2];
#pragma unroll
    for (int mi = 0; mi < 4; ++mi)
#pragma unroll
      for (int kk = 0; kk < 2; ++kk) {
        int rr = wm * 64 + mi * 16 + (lane & 15);
        int w = kk * 64 + ((lane >> 4) << 4);
        af[mi][kk] = *(const bf16x8*)(sA + (size_t)rr * 128 + (w ^ ((rr & 7) << 4)));
        int r2 = wn * 64 + mi * 16 + (lane & 15);
        bfr[mi][kk] = *(const bf16x8*)(sB + (size_t)r2 * 128 + (w ^ ((r2 & 7) << 4)));
      }
#pragma unroll
    for (int kk = 0; kk < 2; ++kk)
#pragma unroll
      for (int mi = 0; mi < 4; ++mi)
#pragma unroll
        for (int ni = 0; ni < 4; ++ni)
          acc[mi][ni] =
              __builtin_amdgcn_mfma_f32_16x16x32_bf16(af[mi][kk], bfr[ni][kk], acc[mi][ni], 0, 0, 0);
    __syncthreads();
  }

  float bs[4];
#pragma unroll
  for (int ni = 0; ni < 4; ++ni) bs[ni] = bias[n0 + wn * 64 + ni * 16 + (lane & 15)];

#pragma unroll
  for (int mi = 0; mi < 4; ++mi)
#pragma unroll
    for (int ni = 0; ni < 4; ++ni)
#pragma unroll
      for (int j = 0; j < 4; ++j) {
        int row = wm * 64 + mi * 16 + ((lane >> 4) << 2) + j;
        int col = wn * 64 + ni * 16 + (lane & 15);
        int m = m0 + row, n = n0 + col;
        float val = acc[mi][ni][j] + bs[ni];
        if (isQ) {
          val *= SCALE_F;
          int bb = m >> 11, t = m & 2047, hh = n >> 6, d = n & 63;
          Qout[(((size_t)(bb * 16 + hh) * 2048 + t) << 6) + d] = (bf16)val;
        } else {
          if (n < 1024) {
            int hh = n >> 6, d = n & 63;
            Kout[(((size_t)hh * 512 + m) << 6) + d] = (bf16)(val * SCALE_F);
          } else {
            int n2 = n - 1024;
            int hh = n2 >> 6, d = n2 & 63;
            Vout[(((size_t)hh * 64 + d) << 9) + m] = (bf16)val;
          }
        }
      }
}

// Out-proj: Z = Y @ out_w^T + out_b   (M=8192, N=1024, K=1024)
__global__ __launch_bounds__(256, 2) void gemm_out(const bf16* __restrict__ A,
                                                   const bf16* __restrict__ Bw,
                                                   const float* __restrict__ bias,
                                                   bf16* __restrict__ out0) {
  __shared__ __align__(16) char sA[16384];
  __shared__ __align__(16) char sB[16384];
  const int tid = threadIdx.x;
  const int lane = tid & 63;
  const int wave = tid >> 6;
  const int wm = wave >> 1, wn = wave & 1;
  const int m0 = blockIdx.x * 128, n0 = blockIdx.y * 128;
  f32x4 acc[4][4] = {};

  for (int kt = 0; kt < 1024; kt += 64) {
#pragma unroll
    for (int j = 0; j < 4; ++j) {
      int i = tid + j * 256;
      int r = i >> 3, q = i & 7;
      int so = (q ^ (r & 7)) << 4;
      load_lds16((const char*)(A + (size_t)(m0 + r) * 1024 + kt) + so, sA + (size_t)i * 16);
      load_lds16((const char*)(Bw + (size_t)(n0 + r) * 1024 + kt) + so, sB + (size_t)i * 16);
    }
    asm volatile("s_waitcnt vmcnt(0)" ::: "memory");
    __syncthreads();
    bf16x8 af[4][2], bfr[4][2];
#pragma unroll
    for (int mi = 0; mi < 4; ++mi)
#pragma unroll
      for (int kk = 0; kk < 2; ++kk) {
        int rr = wm * 64 + mi * 16 + (lane & 15);
        int w = kk * 64 + ((lane >> 4) << 4);
        af[mi][kk] = *(const bf16x8*)(sA + (size_t)rr * 128 + (w ^ ((rr & 7) << 4)));
        int r2 = wn * 64 + mi * 16 + (lane & 15);
        bfr[mi][kk] = *(const bf16x8*)(sB + (size_t)r2 * 128 + (w ^ ((r2 & 7) << 4)));
      }
#pragma unroll
    for (int kk = 0; kk < 2; ++kk)
#pragma unroll
      for (int mi = 0; mi < 4; ++mi)
#pragma unroll
        for (int ni = 0; ni < 4; ++ni)
          acc[mi][ni] =
              __builtin_amdgcn_mfma_f32_16x16x32_bf16(af[mi][kk], bfr[ni][kk], acc[mi][ni], 0, 0, 0);
    __syncthreads();
  }

  float bs[4];
#pragma unroll
  for (int ni = 0; ni < 4; ++ni) bs[ni] = bias[n0 + wn * 64 + ni * 16 + (lane & 15)];
#pragma unroll
  for (int mi = 0; mi < 4; ++mi)
#pragma unroll
    for (int ni = 0; ni < 4; ++ni)
#pragma unroll
      for (int j = 0; j < 4; ++j) {
        int row = wm * 64 + mi * 16 + ((lane >> 4) << 2) + j;
        int col = wn * 64 + ni * 16 + (lane & 15);
        out0[(size_t)(m0 + row) * 1024 + n0 + col] = (bf16)(acc[mi][ni][j] + bs[ni]);
      }
}

// ---------------- attention v3 ----------------
// One block = (b, h, 64 q-rows), 512 threads (8 waves). LDS 75776 B:
//   [0,65536): P (64 q-rows x 1024B, quad-swizzled) ; reused as O f32 (64 x 256B) at the end
//   [65536,73728): Q staging (64 rows x 128B, swizzled)
//   [73728,75776): per-wave partial softmax sums [64 q][8 wv] f32
// Swapped QK^T (S^T: col=q), constant-shift softmax (exact), f32 shfl row-sums,
// K fragments preloaded from global before Q-stage wait, V fragments preloaded
// into registers (va[16], 64 VGPR) before the P barrier so PV is pure LDS+MFMA.
__global__ __launch_bounds__(512, 4) void attn_kernel(const bf16* __restrict__ Q,
                                                      const bf16* __restrict__ Kw,
                                                      const bf16* __restrict__ Vt,
                                                      bf16* __restrict__ Y) {
  __shared__ __align__(16) char lds[75776];
  const int tid = threadIdx.x;
  const int lane = tid & 63;
  const int wv = tid >> 6;
  const int g = lane >> 4;   // quarter-group 0..3
  const int lr = lane & 15;  // row/col within 16
  const int t0 = blockIdx.x * 64;
  const int bh = blockIdx.y;
  const int b = bh >> 4, h = bh & 15;

  // K fragments: issued first, arrive under Q-stage wait. key = 64*wv + 16*mi + lr
  const bf16* Kh = Kw + (size_t)h * 512 * 64;
  bf16x8 ka[2][4];
#pragma unroll
  for (int kk = 0; kk < 2; ++kk)
#pragma unroll
    for (int mi = 0; mi < 4; ++mi) {
      int key = wv * 64 + mi * 16 + lr;
      ka[kk][mi] = *(const bf16x8*)((const char*)Kh + (size_t)key * 128 + kk * 64 + g * 16);
    }

  // stage Q tile (64 rows x 128B) pre-swizzled -> swizzled LDS
  {
    const bf16* Qh = Q + ((size_t)(b * 16 + h) * 2048 + t0) * 64;
    int r = tid >> 3, c = tid & 7;
    load_lds16((const char*)Qh + r * 128 + ((c * 16) ^ ((r & 7) << 4)),
               lds + 65536 + (size_t)tid * 16);
  }
  asm volatile("s_waitcnt vmcnt(0)" ::: "memory");
  __syncthreads();

  // QK^T per q-block: acc[mi][j] = S^T[key=64wv+16mi+4g+j][q=16ni+lr]; pack+sum immediately.
  float psum[4];
#pragma unroll
  for (int ni = 0; ni < 4; ++ni) {
    int q = ni * 16 + lr;
    f32x4 acc[4] = {};
#pragma unroll
    for (int kk = 0; kk < 2; ++kk) {
      bf16x8 qb = *(const bf16x8*)(lds + 65536 + (size_t)q * 128 +
                                   ((kk * 64 + g * 16) ^ ((q & 7) << 4)));
#pragma unroll
      for (int mi = 0; mi < 4; ++mi)
        acc[mi] = __builtin_amdgcn_mfma_f32_16x16x32_bf16(ka[kk][mi], qb, acc[mi], 0, 0, 0);
    }
    float ps = 0.f;
#pragma unroll
    for (int mi = 0; mi < 4; ++mi) {
      bf16x4 w;
#pragma unroll
      for (int j = 0; j < 4; ++j) {
        float p = __expf(acc[mi][j] - 16.0f);  // constant shift: exact for softmax
        ps += p;
        w[j] = (bf16)p;
      }
      *(bf16x4*)(lds + (size_t)q * 1024 + ((wv * 128 + mi * 32 + g * 8) ^ ((q & 7) << 4))) = w;
    }
    ps += __shfl_xor(ps, 16);
    ps += __shfl_xor(ps, 32);
    psum[ni] = ps;  // full sum over this wave's 64 keys, all lanes
  }
  if (lane < 16) {
#pragma unroll
    for (int ni = 0; ni < 4; ++ni)
      *(float*)(lds + 73728 + (((ni * 16 + lr) * 8 + wv) << 2)) = psum[ni];
  }

  // preload V fragments (registers; arrive under the barrier). d = (wv>>1)*16 + lr
  const bf16* Vh = Vt + (size_t)h * 64 * 512;
  const int mi_o = wv >> 1;
  const int d = mi_o * 16 + lr;
  bf16x8 va[16];
#pragma unroll
  for (int kk = 0; kk < 16; ++kk)
    va[kk] = *(const bf16x8*)((const char*)Vh + (size_t)d * 1024 + kk * 64 + g * 16);
  __syncthreads();

  // PV: pure LDS + MFMA. wave -> d-block mi_o, q-blocks {wv&1 ? 2,3 : 0,1}
  const int q0 = (wv & 1) * 32 + lr, q1 = q0 + 16;
  f32x4 o0 = {}, o1 = {};
#pragma unroll
  for (int kk = 0; kk < 16; ++kk) {
    bf16x8 p0 = *(const bf16x8*)(lds + (size_t)q0 * 1024 + ((kk * 64 + g * 16) ^ ((q0 & 7) << 4)));
    bf16x8 p1 = *(const bf16x8*)(lds + (size_t)q1 * 1024 + ((kk * 64 + g * 16) ^ ((q1 & 7) << 4)));
    o0 = __builtin_amdgcn_mfma_f32_16x16x32_bf16(va[kk], p0, o0, 0, 0, 0);
    o1 = __builtin_amdgcn_mfma_f32_16x16x32_bf16(va[kk], p1, o1, 0, 0, 0);
  }
  __syncthreads();  // all P reads complete; P region reusable for O

  // softmax denominators from the partial-sum table
  f32x4 sa0 = *(const f32x4*)(lds + 73728 + q0 * 32);
  f32x4 sb0 = *(const f32x4*)(lds + 73728 + q0 * 32 + 16);
  f32x4 sa1 = *(const f32x4*)(lds + 73728 + q1 * 32);
  f32x4 sb1 = *(const f32x4*)(lds + 73728 + q1 * 32 + 16);
  float s0v = ((sa0[0] + sa0[1]) + (sa0[2] + sa0[3])) + ((sb0[0] + sb0[1]) + (sb0[2] + sb0[3]));
  float s1v = ((sa1[0] + sa1[1]) + (sa1[2] + sa1[3])) + ((sb1[0] + sb1[1]) + (sb1[2] + sb1[3]));

  // normalize, write O transposed to LDS as O[q][d] f32 (row 256B, quad-swizzled)
  {
    float i0 = 1.0f / s0v, i1 = 1.0f / s1v;
    int byt = mi_o * 64 + g * 16;
    f32x4 w0, w1;
#pragma unroll
    for (int j = 0; j < 4; ++j) {
      w0[j] = o0[j] * i0;
      w1[j] = o1[j] * i1;
    }
    *(f32x4*)(lds + (size_t)q0 * 256 + (byt ^ ((q0 & 7) << 4))) = w0;
    *(f32x4*)(lds + (size_t)q1 * 256 + (byt ^ ((q1 & 7) << 4))) = w1;
  }
  __syncthreads();

  // coalesced store: thread -> (q = tid>>3, 8 d's)
  {
    int q = tid >> 3, sub = tid & 7;
    int base = sub * 32;
    f32x4 a = *(const f32x4*)(lds + (size_t)q * 256 + (base ^ ((q & 7) << 4)));
    f32x4 c = *(const f32x4*)(lds + (size_t)q * 256 + ((base + 16) ^ ((q & 7) << 4)));
    bf16x8 w;
#pragma unroll
    for (int j = 0; j < 4; ++j) {
      w[j] = (bf16)a[j];
      w[4 + j] = (bf16)c[j];
    }
    *(bf16x8*)((char*)Y + (((size_t)(b * 2048 + t0 + q) * 1024 + h * 64 + sub * 8) * 2)) = w;
  }
}

// ---------------- launch ----------------

extern "C" void kernel_launch(void* const* d_in, const int* in_sizes, int n_in, void* d_out,
                              int out_size, void* d_ws, size_t ws_size, hipStream_t stream) {
  const float* inpt = (const float*)d_in[0];
  const float* aux = (const float*)d_in[1];
  const float* q_w = (const float*)d_in[2];
  const float* q_b = (const float*)d_in[3];
  const float* kv_w = (const float*)d_in[4];
  const float* kv_b = (const float*)d_in[5];
  const float* out_w = (const float*)d_in[6];
  const float* out_b = (const float*)d_in[7];
  float* out = (float*)d_out;
  char* ws = (char*)d_ws;
  bf16* X = (bf16*)(ws + 0);              // 16MB: X bf16 ; reused as attn-out Y
  bf16* QZ = (bf16*)(ws + (16u << 20));   // 16MB: Q (B,H,T,D) ; reused as Z
  bf16* qwb = (bf16*)(ws + (32u << 20));  // 2MB
  bf16* kvwb = (bf16*)(ws + (34u << 20)); // 4MB
  bf16* owb = (bf16*)(ws + (38u << 20));  // 2MB
  bf16* auxb = (bf16*)(ws + (40u << 20)); // 1MB
  bf16* Kws = (bf16*)(ws + (41u << 20));  // 1MB (H,L,D)
  bf16* Vtw = (bf16*)(ws + (42u << 20));  // 1MB (H,D,L)

  cvt_all<<<4608, 256, 0, stream>>>(q_w, qwb, kv_w, kvwb, out_w, owb, aux, auxb);
  transpose_in<<<dim3(64, 32, 4), dim3(32, 8), 0, stream>>>(inpt, X);

  gemm_qkv<<<576, 256, 0, stream>>>(X, qwb, q_b, QZ, auxb, kvwb, kv_b, Kws, Vtw);
  attn_kernel<<<dim3(32, 64), 512, 0, stream>>>(QZ, Kws, Vtw, X /* Y reuses X */);
  gemm_out<<<dim3(64, 8), 256, 0, stream>>>(X, owb, out_b, QZ /* Z reuses Q */);
  residual_out<<<dim3(64, 32, 4), dim3(32, 8), 0, stream>>>(inpt, QZ, out);
}

// Round 4
// 205.557 us; speedup vs baseline: 1.2566x; 1.0833x over previous
//
#include <hip/hip_runtime.h>
#include <cstdint>
#include <cstddef>

typedef __bf16 bf16;
typedef __bf16 bf16x4 __attribute__((ext_vector_type(4)));
typedef __bf16 bf16x8 __attribute__((ext_vector_type(8)));
typedef float f32x4 __attribute__((ext_vector_type(4)));

static constexpr float SCALE_F = 0.35355339059327373f;  // (1024/16)^-0.25

#define AS1 __attribute__((address_space(1)))
#define AS3 __attribute__((address_space(3)))

__device__ __forceinline__ void load_lds16(const void* g, void* l) {
  __builtin_amdgcn_global_load_lds((AS1 void*)g, (AS3 void*)l, 16, 0, 0);
}

// ---------------- fused f32->bf16 conversion (4 buffers, one launch) ----------------

__global__ void cvt_all(const float* __restrict__ a, bf16* __restrict__ oa,
                        const float* __restrict__ b, bf16* __restrict__ ob,
                        const float* __restrict__ c, bf16* __restrict__ oc,
                        const float* __restrict__ d, bf16* __restrict__ od) {
  int i = blockIdx.x * blockDim.x + threadIdx.x;  // float4 index
  const float* src;
  bf16* dst;
  int off;
  if (i < 262144) { src = a; dst = oa; off = i; }
  else if (i < 786432) { src = b; dst = ob; off = i - 262144; }
  else if (i < 1048576) { src = c; dst = oc; off = i - 786432; }
  else { src = d; dst = od; off = i - 1048576; }
  float4 v = reinterpret_cast<const float4*>(src)[off];
  bf16x4 o;
  o[0] = (bf16)v.x; o[1] = (bf16)v.y; o[2] = (bf16)v.z; o[3] = (bf16)v.w;
  reinterpret_cast<bf16x4*>(dst)[off] = o;
}

// inpt (B, C, T) f32  ->  X (B*T, C) bf16
__global__ void transpose_in(const float* __restrict__ inpt, bf16* __restrict__ X) {
  __shared__ float tile[32][33];
  int b = blockIdx.z;
  int t0 = blockIdx.x * 32, c0 = blockIdx.y * 32;
  int tx = threadIdx.x, ty = threadIdx.y;  // 32x8
  const float* src = inpt + ((size_t)b * 1024 + c0) * 2048 + t0;
#pragma unroll
  for (int i = 0; i < 4; ++i) tile[ty + i * 8][tx] = src[(size_t)(ty + i * 8) * 2048 + tx];
  __syncthreads();
  bf16* dst = X + ((size_t)b * 2048 + t0) * 1024 + c0;
#pragma unroll
  for (int i = 0; i < 4; ++i) dst[(size_t)(ty + i * 8) * 1024 + tx] = (bf16)tile[tx][ty + i * 8];
}

// out (B, C, T) f32 = inpt + Z(B*T, C)^T
__global__ void residual_out(const float* __restrict__ inpt, const bf16* __restrict__ Z,
                             float* __restrict__ out) {
  __shared__ float tile[32][33];
  int b = blockIdx.z;
  int t0 = blockIdx.x * 32, c0 = blockIdx.y * 32;
  int tx = threadIdx.x, ty = threadIdx.y;
  const bf16* zsrc = Z + ((size_t)b * 2048 + t0) * 1024 + c0;
#pragma unroll
  for (int i = 0; i < 4; ++i) tile[ty + i * 8][tx] = (float)zsrc[(size_t)(ty + i * 8) * 1024 + tx];
  __syncthreads();
  size_t ob = ((size_t)b * 1024 + c0) * 2048 + t0;
#pragma unroll
  for (int i = 0; i < 4; ++i) {
    size_t idx = ob + (size_t)(ty + i * 8) * 2048 + tx;
    out[idx] = inpt[idx] + tile[tx][ty + i * 8];
  }
}

// ---------------- GEMM (128x128 tile, K=1024, B^T weights) ----------------

// Fused Q-proj + KV-proj: blocks [0,512) do Q (M=8192,N=1024), blocks [512,576) do KV.
// V epilogue writes Vt with PERMUTED key order: slot = G*32 + gq*8 + m*4 + j
// (key = G*32 + m*16 + gq*4 + j). Softmax sums over keys -> any fixed permutation
// is exact; this one makes P (as produced in-lane by swapped QK^T) directly the
// B-operand of the PV 16x16x32 MFMA. K stays in natural order.
__global__ __launch_bounds__(256, 2) void gemm_qkv(
    const bf16* __restrict__ X, const bf16* __restrict__ qwb, const float* __restrict__ q_b,
    bf16* __restrict__ Qout, const bf16* __restrict__ auxb, const bf16* __restrict__ kvwb,
    const float* __restrict__ kv_b, bf16* __restrict__ Kout, bf16* __restrict__ Vout) {
  __shared__ __align__(16) char sA[16384];  // 128 x 64 bf16, XOR-swizzled rows
  __shared__ __align__(16) char sB[16384];
  const int tid = threadIdx.x;
  const int lane = tid & 63;
  const int wave = tid >> 6;
  const int wm = wave >> 1, wn = wave & 1;
  const int bid = blockIdx.x;
  const bool isQ = bid < 512;
  const bf16 *A, *Bw;
  const float* bias;
  int m0, n0;
  if (isQ) {
    A = X; Bw = qwb; bias = q_b;
    m0 = (bid >> 3) * 128; n0 = (bid & 7) * 128;
  } else {
    int b2 = bid - 512;
    A = auxb; Bw = kvwb; bias = kv_b;
    m0 = (b2 & 3) * 128; n0 = (b2 >> 2) * 128;
  }
  f32x4 acc[4][4] = {};

  for (int kt = 0; kt < 1024; kt += 64) {
#pragma unroll
    for (int j = 0; j < 4; ++j) {
      int i = tid + j * 256;
      int r = i >> 3, q = i & 7;
      int so = (q ^ (r & 7)) << 4;
      load_lds16((const char*)(A + (size_t)(m0 + r) * 1024 + kt) + so, sA + (size_t)i * 16);
      load_lds16((const char*)(Bw + (size_t)(n0 + r) * 1024 + kt) + so, sB + (size_t)i * 16);
    }
    asm volatile("s_waitcnt vmcnt(0)" ::: "memory");
    __syncthreads();
    bf16x8 af[4][2], bfr[4][2];
#pragma unroll
    for (int mi = 0; mi < 4; ++mi)
#pragma unroll
      for (int kk = 0; kk < 2; ++kk) {
        int rr = wm * 64 + mi * 16 + (lane & 15);
        int w = kk * 64 + ((lane >> 4) << 4);
        af[mi][kk] = *(const bf16x8*)(sA + (size_t)rr * 128 + (w ^ ((rr & 7) << 4)));
        int r2 = wn * 64 + mi * 16 + (lane & 15);
        bfr[mi][kk] = *(const bf16x8*)(sB + (size_t)r2 * 128 + (w ^ ((r2 & 7) << 4)));
      }
#pragma unroll
    for (int kk = 0; kk < 2; ++kk)
#pragma unroll
      for (int mi = 0; mi < 4; ++mi)
#pragma unroll
        for (int ni = 0; ni < 4; ++ni)
          acc[mi][ni] =
              __builtin_amdgcn_mfma_f32_16x16x32_bf16(af[mi][kk], bfr[ni][kk], acc[mi][ni], 0, 0, 0);
    __syncthreads();
  }

  float bs[4];
#pragma unroll
  for (int ni = 0; ni < 4; ++ni) bs[ni] = bias[n0 + wn * 64 + ni * 16 + (lane & 15)];

#pragma unroll
  for (int mi = 0; mi < 4; ++mi)
#pragma unroll
    for (int ni = 0; ni < 4; ++ni)
#pragma unroll
      for (int j = 0; j < 4; ++j) {
        int row = wm * 64 + mi * 16 + ((lane >> 4) << 2) + j;
        int col = wn * 64 + ni * 16 + (lane & 15);
        int m = m0 + row, n = n0 + col;
        float val = acc[mi][ni][j] + bs[ni];
        if (isQ) {
          val *= SCALE_F;
          int bb = m >> 11, t = m & 2047, hh = n >> 6, d = n & 63;
          Qout[(((size_t)(bb * 16 + hh) * 2048 + t) << 6) + d] = (bf16)val;
        } else {
          if (n < 1024) {
            int hh = n >> 6, d = n & 63;
            Kout[(((size_t)hh * 512 + m) << 6) + d] = (bf16)(val * SCALE_F);
          } else {
            int n2 = n - 1024;
            int hh = n2 >> 6, d = n2 & 63;
            // permuted key slot (see comment above)
            int sl = (m & 0x1E0) | (((m >> 2) & 3) << 3) | (((m >> 4) & 1) << 2) | (m & 3);
            Vout[(((size_t)hh * 64 + d) << 9) + sl] = (bf16)val;
          }
        }
      }
}

// Out-proj: Z = Y @ out_w^T + out_b   (M=8192, N=1024, K=1024)
__global__ __launch_bounds__(256, 2) void gemm_out(const bf16* __restrict__ A,
                                                   const bf16* __restrict__ Bw,
                                                   const float* __restrict__ bias,
                                                   bf16* __restrict__ out0) {
  __shared__ __align__(16) char sA[16384];
  __shared__ __align__(16) char sB[16384];
  const int tid = threadIdx.x;
  const int lane = tid & 63;
  const int wave = tid >> 6;
  const int wm = wave >> 1, wn = wave & 1;
  const int m0 = blockIdx.x * 128, n0 = blockIdx.y * 128;
  f32x4 acc[4][4] = {};

  for (int kt = 0; kt < 1024; kt += 64) {
#pragma unroll
    for (int j = 0; j < 4; ++j) {
      int i = tid + j * 256;
      int r = i >> 3, q = i & 7;
      int so = (q ^ (r & 7)) << 4;
      load_lds16((const char*)(A + (size_t)(m0 + r) * 1024 + kt) + so, sA + (size_t)i * 16);
      load_lds16((const char*)(Bw + (size_t)(n0 + r) * 1024 + kt) + so, sB + (size_t)i * 16);
    }
    asm volatile("s_waitcnt vmcnt(0)" ::: "memory");
    __syncthreads();
    bf16x8 af[4][2], bfr[4][2];
#pragma unroll
    for (int mi = 0; mi < 4; ++mi)
#pragma unroll
      for (int kk = 0; kk < 2; ++kk) {
        int rr = wm * 64 + mi * 16 + (lane & 15);
        int w = kk * 64 + ((lane >> 4) << 4);
        af[mi][kk] = *(const bf16x8*)(sA + (size_t)rr * 128 + (w ^ ((rr & 7) << 4)));
        int r2 = wn * 64 + mi * 16 + (lane & 15);
        bfr[mi][kk] = *(const bf16x8*)(sB + (size_t)r2 * 128 + (w ^ ((r2 & 7) << 4)));
      }
#pragma unroll
    for (int kk = 0; kk < 2; ++kk)
#pragma unroll
      for (int mi = 0; mi < 4; ++mi)
#pragma unroll
        for (int ni = 0; ni < 4; ++ni)
          acc[mi][ni] =
              __builtin_amdgcn_mfma_f32_16x16x32_bf16(af[mi][kk], bfr[ni][kk], acc[mi][ni], 0, 0, 0);
    __syncthreads();
  }

  float bs[4];
#pragma unroll
  for (int ni = 0; ni < 4; ++ni) bs[ni] = bias[n0 + wn * 64 + ni * 16 + (lane & 15)];
#pragma unroll
  for (int mi = 0; mi < 4; ++mi)
#pragma unroll
    for (int ni = 0; ni < 4; ++ni)
#pragma unroll
      for (int j = 0; j < 4; ++j) {
        int row = wm * 64 + mi * 16 + ((lane >> 4) << 2) + j;
        int col = wn * 64 + ni * 16 + (lane & 15);
        out0[(size_t)(m0 + row) * 1024 + n0 + col] = (bf16)(acc[mi][ni][j] + bs[ni]);
      }
}

// ---------------- attention v4: barrier-free flash per wave ----------------
// Block = (b, h, 512-t chunk), 512 threads (8 waves), LDS 128KB (1 block/CU):
//   K [0,65536): 512 keys x 128B rows, XOR-swizzled
//   V [65536,131072): 64 d-rows x 1024B (keys, PERMUTED slot order), XOR-swizzled
// One barrier (after staging). Each wave independently owns 64 q-rows (4 sets of
// 16): per 32-key group, reads 4 K-frags + 4 V-frags (shared across all 4 sets),
// S^T = mfma(K, Q) keeps P in-lane; exp(S-16) (constant shift, exact); PV uses
// pb directly as B-operand thanks to the permuted Vt slot order. Row sums in
// registers, 2 shfl_xor at the end. 2-stage pipelined group loop.
struct Frags {
  bf16x8 ka[2][2];
  bf16x8 va[4];
};

__device__ __forceinline__ void load_frags(Frags& f, const char* lds, int G, int lr, int g) {
  const int swz = (lr & 7) << 4;
#pragma unroll
  for (int m = 0; m < 2; ++m)
#pragma unroll
    for (int kk = 0; kk < 2; ++kk)
      f.ka[m][kk] =
          *(const bf16x8*)(lds + (size_t)(G * 32 + m * 16 + lr) * 128 + ((kk * 64 + g * 16) ^ swz));
#pragma unroll
  for (int db = 0; db < 4; ++db)
    f.va[db] = *(const bf16x8*)(lds + 65536 + (size_t)(db * 16 + lr) * 1024 +
                                ((G * 64 + g * 16) ^ swz));
}

__device__ __forceinline__ void compute_group(const Frags& f, const bf16x8 (&qf)[4][2],
                                              f32x4 (&oacc)[4][4], float (&psum)[4]) {
  f32x4 sa[4][2] = {};
#pragma unroll
  for (int s = 0; s < 4; ++s)
#pragma unroll
    for (int m = 0; m < 2; ++m) {
      sa[s][m] = __builtin_amdgcn_mfma_f32_16x16x32_bf16(f.ka[m][0], qf[s][0], sa[s][m], 0, 0, 0);
      sa[s][m] = __builtin_amdgcn_mfma_f32_16x16x32_bf16(f.ka[m][1], qf[s][1], sa[s][m], 0, 0, 0);
    }
  bf16x8 pb[4];
#pragma unroll
  for (int s = 0; s < 4; ++s)
#pragma unroll
    for (int m = 0; m < 2; ++m)
#pragma unroll
      for (int j = 0; j < 4; ++j) {
        float p = __expf(sa[s][m][j] - 16.0f);
        psum[s] += p;
        pb[s][m * 4 + j] = (bf16)p;
      }
#pragma unroll
  for (int s = 0; s < 4; ++s)
#pragma unroll
    for (int db = 0; db < 4; ++db)
      oacc[s][db] = __builtin_amdgcn_mfma_f32_16x16x32_bf16(f.va[db], pb[s], oacc[s][db], 0, 0, 0);
}

__global__ __launch_bounds__(512, 2) void attn_kernel(const bf16* __restrict__ Q,
                                                      const bf16* __restrict__ Kw,
                                                      const bf16* __restrict__ Vt,
                                                      bf16* __restrict__ Y) {
  __shared__ __align__(16) char lds[131072];
  const int tid = threadIdx.x;
  const int lane = tid & 63;
  const int wv = tid >> 6;
  const int g = lane >> 4, lr = lane & 15;
  const int bix = blockIdx.x;
  const int b = bix >> 6, h = (bix >> 2) & 15, tc = bix & 3;

  const bf16* Kh = Kw + (size_t)h * 512 * 64;
  const bf16* Vh = Vt + (size_t)h * 64 * 512;
  // stage K (64KB): rows 128B, pre-swizzled source
#pragma unroll
  for (int j = 0; j < 8; ++j) {
    int i = tid + j * 512;
    int r = i >> 3, c = i & 7;
    load_lds16((const char*)Kh + r * 128 + ((c * 16) ^ ((r & 7) << 4)), lds + (size_t)i * 16);
  }
  // stage V (64KB): rows 1024B, pre-swizzled source
#pragma unroll
  for (int j = 0; j < 8; ++j) {
    int i = tid + j * 512;
    int r = i >> 6, c = i & 63;
    load_lds16((const char*)Vh + r * 1024 + ((c * 16) ^ ((r & 7) << 4)),
               lds + 65536 + (size_t)i * 16);
  }

  // Q fragments straight from global (HBM, overlaps staging)
  const int tb = tc * 512 + wv * 64;
  const bf16* Qh = Q + ((size_t)(b * 16 + h) * 2048 + tb) * 64;
  bf16x8 qf[4][2];
#pragma unroll
  for (int s = 0; s < 4; ++s)
#pragma unroll
    for (int kk = 0; kk < 2; ++kk)
      qf[s][kk] = *(const bf16x8*)((const char*)Qh + (s * 16 + lr) * 128 + kk * 64 + g * 16);

  asm volatile("s_waitcnt vmcnt(0)" ::: "memory");
  __syncthreads();  // the only barrier

  f32x4 oacc[4][4] = {};  // [set][db]
  float psum[4] = {};

  Frags fA, fB;
  load_frags(fA, lds, 0, lr, g);
#pragma unroll 1
  for (int G = 0; G < 16; G += 2) {
    load_frags(fB, lds, G + 1, lr, g);
    compute_group(fA, qf, oacc, psum);
    if (G + 2 < 16) load_frags(fA, lds, G + 2, lr, g);
    compute_group(fB, qf, oacc, psum);
  }

  // finalize: sum over lane quarters, normalize, store
#pragma unroll
  for (int s = 0; s < 4; ++s) {
    float ssum = psum[s];
    ssum += __shfl_xor(ssum, 16);
    ssum += __shfl_xor(ssum, 32);
    float inv = 1.0f / ssum;
    int t = tb + s * 16 + lr;
    char* yrow = (char*)Y + ((size_t)(b * 2048 + t) * 1024 + h * 64) * 2;
#pragma unroll
    for (int db = 0; db < 4; ++db) {
      bf16x4 w;
#pragma unroll
      for (int j = 0; j < 4; ++j) w[j] = (bf16)(oacc[s][db][j] * inv);
      *(bf16x4*)(yrow + (db * 16 + g * 4) * 2) = w;
    }
  }
}

// ---------------- launch ----------------

extern "C" void kernel_launch(void* const* d_in, const int* in_sizes, int n_in, void* d_out,
                              int out_size, void* d_ws, size_t ws_size, hipStream_t stream) {
  const float* inpt = (const float*)d_in[0];
  const float* aux = (const float*)d_in[1];
  const float* q_w = (const float*)d_in[2];
  const float* q_b = (const float*)d_in[3];
  const float* kv_w = (const float*)d_in[4];
  const float* kv_b = (const float*)d_in[5];
  const float* out_w = (const float*)d_in[6];
  const float* out_b = (const float*)d_in[7];
  float* out = (float*)d_out;
  char* ws = (char*)d_ws;
  bf16* X = (bf16*)(ws + 0);              // 16MB: X bf16 ; reused as attn-out Y
  bf16* QZ = (bf16*)(ws + (16u << 20));   // 16MB: Q (B,H,T,D) ; reused as Z
  bf16* qwb = (bf16*)(ws + (32u << 20));  // 2MB
  bf16* kvwb = (bf16*)(ws + (34u << 20)); // 4MB
  bf16* owb = (bf16*)(ws + (38u << 20));  // 2MB
  bf16* auxb = (bf16*)(ws + (40u << 20)); // 1MB
  bf16* Kws = (bf16*)(ws + (41u << 20));  // 1MB (H,L,D)
  bf16* Vtw = (bf16*)(ws + (42u << 20));  // 1MB (H,D,L) permuted slots

  cvt_all<<<4608, 256, 0, stream>>>(q_w, qwb, kv_w, kvwb, out_w, owb, aux, auxb);
  transpose_in<<<dim3(64, 32, 4), dim3(32, 8), 0, stream>>>(inpt, X);

  gemm_qkv<<<576, 256, 0, stream>>>(X, qwb, q_b, QZ, auxb, kvwb, kv_b, Kws, Vtw);
  attn_kernel<<<256, 512, 0, stream>>>(QZ, Kws, Vtw, X /* Y reuses X */);
  gemm_out<<<dim3(64, 8), 256, 0, stream>>>(X, owb, out_b, QZ /* Z reuses Q */);
  residual_out<<<dim3(64, 32, 4), dim3(32, 8), 0, stream>>>(inpt, QZ, out);
}

// Round 5
// 194.131 us; speedup vs baseline: 1.3306x; 1.0589x over previous
//
#include <hip/hip_runtime.h>
#include <cstdint>
#include <cstddef>

typedef __bf16 bf16;
typedef __bf16 bf16x4 __attribute__((ext_vector_type(4)));
typedef __bf16 bf16x8 __attribute__((ext_vector_type(8)));
typedef float f32x4 __attribute__((ext_vector_type(4)));

static constexpr float SCALE_F = 0.35355339059327373f;  // (1024/16)^-0.25

#define AS1 __attribute__((address_space(1)))
#define AS3 __attribute__((address_space(3)))

__device__ __forceinline__ void load_lds16(const void* g, void* l) {
  __builtin_amdgcn_global_load_lds((AS1 void*)g, (AS3 void*)l, 16, 0, 0);
}

// ---------------- prep: fused f32->bf16 converts (4 buffers) + input transpose ----------------
// blocks [0,4608): cvt; blocks [4608,12800): inpt (B,C,T) f32 -> X (B*T,C) bf16
__global__ void prep(const float* __restrict__ q_w, bf16* __restrict__ qwb,
                     const float* __restrict__ kv_w, bf16* __restrict__ kvwb,
                     const float* __restrict__ out_w, bf16* __restrict__ owb,
                     const float* __restrict__ aux, bf16* __restrict__ auxb,
                     const float* __restrict__ inpt, bf16* __restrict__ X) {
  const int bid = blockIdx.x;
  const int tid = threadIdx.x;
  if (bid < 4608) {
    int i = bid * 256 + tid;  // float4 index
    const float* src;
    bf16* dst;
    int off;
    if (i < 262144) { src = q_w; dst = qwb; off = i; }
    else if (i < 786432) { src = kv_w; dst = kvwb; off = i - 262144; }
    else if (i < 1048576) { src = out_w; dst = owb; off = i - 786432; }
    else { src = aux; dst = auxb; off = i - 1048576; }
    float4 v = reinterpret_cast<const float4*>(src)[off];
    bf16x4 o;
    o[0] = (bf16)v.x; o[1] = (bf16)v.y; o[2] = (bf16)v.z; o[3] = (bf16)v.w;
    reinterpret_cast<bf16x4*>(dst)[off] = o;
  } else {
    __shared__ float tile[32][33];
    int tb = bid - 4608;          // 0..8191
    int b = tb >> 11;             // batch
    int rem = tb & 2047;
    int c0 = (rem >> 6) * 32;     // c-tile 0..31
    int t0 = (rem & 63) * 32;     // t-tile 0..63
    int tx = tid & 31, ty = tid >> 5;  // 32x8
    const float* src = inpt + ((size_t)b * 1024 + c0) * 2048 + t0;
#pragma unroll
    for (int i = 0; i < 4; ++i) tile[ty + i * 8][tx] = src[(size_t)(ty + i * 8) * 2048 + tx];
    __syncthreads();
    bf16* dst = X + ((size_t)b * 2048 + t0) * 1024 + c0;
#pragma unroll
    for (int i = 0; i < 4; ++i) dst[(size_t)(ty + i * 8) * 1024 + tx] = (bf16)tile[tx][ty + i * 8];
  }
}

// ---------------- GEMM (128x128 tile, K=1024, B^T weights) ----------------

// Fused Q-proj + KV-proj: blocks [0,512) do Q (M=8192,N=1024), blocks [512,576) do KV.
// V epilogue writes Vt with PERMUTED key order: slot = G*32 + gq*8 + m*4 + j
// (key = G*32 + m*16 + gq*4 + j). Softmax sums over keys -> any fixed permutation
// is exact; this one makes P (as produced in-lane by swapped QK^T) directly the
// B-operand of the PV 16x16x32 MFMA. K stays in natural order.
__global__ __launch_bounds__(256, 3) void gemm_qkv(
    const bf16* __restrict__ X, const bf16* __restrict__ qwb, const float* __restrict__ q_b,
    bf16* __restrict__ Qout, const bf16* __restrict__ auxb, const bf16* __restrict__ kvwb,
    const float* __restrict__ kv_b, bf16* __restrict__ Kout, bf16* __restrict__ Vout) {
  __shared__ __align__(16) char sA[16384];  // 128 x 64 bf16, XOR-swizzled rows
  __shared__ __align__(16) char sB[16384];
  const int tid = threadIdx.x;
  const int lane = tid & 63;
  const int wave = tid >> 6;
  const int wm = wave >> 1, wn = wave & 1;
  const int bid = blockIdx.x;
  const bool isQ = bid < 512;
  const bf16 *A, *Bw;
  const float* bias;
  int m0, n0;
  if (isQ) {
    A = X; Bw = qwb; bias = q_b;
    m0 = (bid >> 3) * 128; n0 = (bid & 7) * 128;
  } else {
    int b2 = bid - 512;
    A = auxb; Bw = kvwb; bias = kv_b;
    m0 = (b2 & 3) * 128; n0 = (b2 >> 2) * 128;
  }
  f32x4 acc[4][4] = {};

  for (int kt = 0; kt < 1024; kt += 64) {
#pragma unroll
    for (int j = 0; j < 4; ++j) {
      int i = tid + j * 256;
      int r = i >> 3, q = i & 7;
      int so = (q ^ (r & 7)) << 4;
      load_lds16((const char*)(A + (size_t)(m0 + r) * 1024 + kt) + so, sA + (size_t)i * 16);
      load_lds16((const char*)(Bw + (size_t)(n0 + r) * 1024 + kt) + so, sB + (size_t)i * 16);
    }
    asm volatile("s_waitcnt vmcnt(0)" ::: "memory");
    __syncthreads();
    bf16x8 af[4][2], bfr[4][2];
#pragma unroll
    for (int mi = 0; mi < 4; ++mi)
#pragma unroll
      for (int kk = 0; kk < 2; ++kk) {
        int rr = wm * 64 + mi * 16 + (lane & 15);
        int w = kk * 64 + ((lane >> 4) << 4);
        af[mi][kk] = *(const bf16x8*)(sA + (size_t)rr * 128 + (w ^ ((rr & 7) << 4)));
        int r2 = wn * 64 + mi * 16 + (lane & 15);
        bfr[mi][kk] = *(const bf16x8*)(sB + (size_t)r2 * 128 + (w ^ ((r2 & 7) << 4)));
      }
#pragma unroll
    for (int kk = 0; kk < 2; ++kk)
#pragma unroll
      for (int mi = 0; mi < 4; ++mi)
#pragma unroll
        for (int ni = 0; ni < 4; ++ni)
          acc[mi][ni] =
              __builtin_amdgcn_mfma_f32_16x16x32_bf16(af[mi][kk], bfr[ni][kk], acc[mi][ni], 0, 0, 0);
    __syncthreads();
  }

  float bs[4];
#pragma unroll
  for (int ni = 0; ni < 4; ++ni) bs[ni] = bias[n0 + wn * 64 + ni * 16 + (lane & 15)];

#pragma unroll
  for (int mi = 0; mi < 4; ++mi)
#pragma unroll
    for (int ni = 0; ni < 4; ++ni)
#pragma unroll
      for (int j = 0; j < 4; ++j) {
        int row = wm * 64 + mi * 16 + ((lane >> 4) << 2) + j;
        int col = wn * 64 + ni * 16 + (lane & 15);
        int m = m0 + row, n = n0 + col;
        float val = acc[mi][ni][j] + bs[ni];
        if (isQ) {
          val *= SCALE_F;
          int bb = m >> 11, t = m & 2047, hh = n >> 6, d = n & 63;
          Qout[(((size_t)(bb * 16 + hh) * 2048 + t) << 6) + d] = (bf16)val;
        } else {
          if (n < 1024) {
            int hh = n >> 6, d = n & 63;
            Kout[(((size_t)hh * 512 + m) << 6) + d] = (bf16)(val * SCALE_F);
          } else {
            int n2 = n - 1024;
            int hh = n2 >> 6, d = n2 & 63;
            // permuted key slot (see comment above)
            int sl = (m & 0x1E0) | (((m >> 2) & 3) << 3) | (((m >> 4) & 1) << 2) | (m & 3);
            Vout[(((size_t)hh * 64 + d) << 9) + sl] = (bf16)val;
          }
        }
      }
}

// Out-proj + residual: out(B,C,T) = inpt + (Y @ out_w^T + out_b)^T
// Epilogue transposes the 128(t) x 128(c) tile through a 64KB LDS buffer
// ([c][t] f32, XOR-swizzled rows) then does coalesced f32x4 read-add-write.
__global__ __launch_bounds__(256, 2) void gemm_outres(const bf16* __restrict__ A,
                                                      const bf16* __restrict__ Bw,
                                                      const float* __restrict__ bias,
                                                      const float* __restrict__ inpt,
                                                      float* __restrict__ out) {
  __shared__ __align__(16) char smem[65536];  // loop: sA=[0,16K), sB=[16K,32K); epi: all 64K
  char* sA = smem;
  char* sB = smem + 16384;
  const int tid = threadIdx.x;
  const int lane = tid & 63;
  const int wave = tid >> 6;
  const int wm = wave >> 1, wn = wave & 1;
  const int g = lane >> 4, lr = lane & 15;
  const int m0 = blockIdx.x * 128, n0 = blockIdx.y * 128;
  f32x4 acc[4][4] = {};

  for (int kt = 0; kt < 1024; kt += 64) {
#pragma unroll
    for (int j = 0; j < 4; ++j) {
      int i = tid + j * 256;
      int r = i >> 3, q = i & 7;
      int so = (q ^ (r & 7)) << 4;
      load_lds16((const char*)(A + (size_t)(m0 + r) * 1024 + kt) + so, sA + (size_t)i * 16);
      load_lds16((const char*)(Bw + (size_t)(n0 + r) * 1024 + kt) + so, sB + (size_t)i * 16);
    }
    asm volatile("s_waitcnt vmcnt(0)" ::: "memory");
    __syncthreads();
    bf16x8 af[4][2], bfr[4][2];
#pragma unroll
    for (int mi = 0; mi < 4; ++mi)
#pragma unroll
      for (int kk = 0; kk < 2; ++kk) {
        int rr = wm * 64 + mi * 16 + lr;
        int w = kk * 64 + (g << 4);
        af[mi][kk] = *(const bf16x8*)(sA + (size_t)rr * 128 + (w ^ ((rr & 7) << 4)));
        int r2 = wn * 64 + mi * 16 + lr;
        bfr[mi][kk] = *(const bf16x8*)(sB + (size_t)r2 * 128 + (w ^ ((r2 & 7) << 4)));
      }
#pragma unroll
    for (int kk = 0; kk < 2; ++kk)
#pragma unroll
      for (int mi = 0; mi < 4; ++mi)
#pragma unroll
        for (int ni = 0; ni < 4; ++ni)
          acc[mi][ni] =
              __builtin_amdgcn_mfma_f32_16x16x32_bf16(af[mi][kk], bfr[ni][kk], acc[mi][ni], 0, 0, 0);
    __syncthreads();
  }

  float bs[4];
#pragma unroll
  for (int ni = 0; ni < 4; ++ni) bs[ni] = bias[n0 + wn * 64 + ni * 16 + lr];

  // acc -> LDS [c][t] f32 (row 512B, XOR-swizzled by c)
#pragma unroll
  for (int mi = 0; mi < 4; ++mi)
#pragma unroll
    for (int ni = 0; ni < 4; ++ni) {
      int c_l = wn * 64 + ni * 16 + lr;
      int tb = (wm * 64 + mi * 16 + g * 4) * 4;  // byte offset of token-quad (16B aligned)
      f32x4 v;
#pragma unroll
      for (int j = 0; j < 4; ++j) v[j] = acc[mi][ni][j] + bs[ni];
      *(f32x4*)(smem + (size_t)c_l * 512 + (tb ^ ((c_l & 31) << 4))) = v;
    }
  __syncthreads();

  // coalesced read-add-write: 4 passes x (32 c-rows, 8 lanes x 16B contiguous per row)
  const int c_r = tid >> 3;
  const int tcol = (tid & 7) * 16;  // byte
  const int b = m0 >> 11, m0t = m0 & 2047;
#pragma unroll
  for (int p = 0; p < 4; ++p) {
    int c = p * 32 + c_r;
    size_t grow = ((size_t)b * 1024 + n0 + c) * 2048 + m0t;  // float index of row base
#pragma unroll
    for (int q = 0; q < 4; ++q) {
      int t = tcol + q * 128;  // byte within 512B row
      f32x4 z = *(const f32x4*)(smem + (size_t)c * 512 + (t ^ ((c & 31) << 4)));
      f32x4 iv = *(const f32x4*)(inpt + grow + (t >> 2));
      f32x4 w;
#pragma unroll
      for (int j = 0; j < 4; ++j) w[j] = iv[j] + z[j];
      *(f32x4*)(out + grow + (t >> 2)) = w;
    }
  }
}

// ---------------- attention v4: barrier-free flash per wave ----------------
// Block = (b, h, 512-t chunk), 512 threads (8 waves), LDS 128KB (1 block/CU):
//   K [0,65536): 512 keys x 128B rows, XOR-swizzled
//   V [65536,131072): 64 d-rows x 1024B (keys, PERMUTED slot order), XOR-swizzled
// One barrier (after staging). Each wave independently owns 64 q-rows (4 sets of
// 16): per 32-key group, reads 4 K-frags + 4 V-frags (shared across all 4 sets),
// S^T = mfma(K, Q) keeps P in-lane; exp(S-16) (constant shift, exact); PV uses
// pb directly as B-operand thanks to the permuted Vt slot order. Row sums in
// registers, 2 shfl_xor at the end. 2-stage pipelined group loop.
struct Frags {
  bf16x8 ka[2][2];
  bf16x8 va[4];
};

__device__ __forceinline__ void load_frags(Frags& f, const char* lds, int G, int lr, int g) {
  const int swz = (lr & 7) << 4;
#pragma unroll
  for (int m = 0; m < 2; ++m)
#pragma unroll
    for (int kk = 0; kk < 2; ++kk)
      f.ka[m][kk] =
          *(const bf16x8*)(lds + (size_t)(G * 32 + m * 16 + lr) * 128 + ((kk * 64 + g * 16) ^ swz));
#pragma unroll
  for (int db = 0; db < 4; ++db)
    f.va[db] = *(const bf16x8*)(lds + 65536 + (size_t)(db * 16 + lr) * 1024 +
                                ((G * 64 + g * 16) ^ swz));
}

__device__ __forceinline__ void compute_group(const Frags& f, const bf16x8 (&qf)[4][2],
                                              f32x4 (&oacc)[4][4], float (&psum)[4]) {
  f32x4 sa[4][2] = {};
#pragma unroll
  for (int s = 0; s < 4; ++s)
#pragma unroll
    for (int m = 0; m < 2; ++m) {
      sa[s][m] = __builtin_amdgcn_mfma_f32_16x16x32_bf16(f.ka[m][0], qf[s][0], sa[s][m], 0, 0, 0);
      sa[s][m] = __builtin_amdgcn_mfma_f32_16x16x32_bf16(f.ka[m][1], qf[s][1], sa[s][m], 0, 0, 0);
    }
  bf16x8 pb[4];
#pragma unroll
  for (int s = 0; s < 4; ++s)
#pragma unroll
    for (int m = 0; m < 2; ++m)
#pragma unroll
      for (int j = 0; j < 4; ++j) {
        float p = __expf(sa[s][m][j] - 16.0f);
        psum[s] += p;
        pb[s][m * 4 + j] = (bf16)p;
      }
#pragma unroll
  for (int s = 0; s < 4; ++s)
#pragma unroll
    for (int db = 0; db < 4; ++db)
      oacc[s][db] = __builtin_amdgcn_mfma_f32_16x16x32_bf16(f.va[db], pb[s], oacc[s][db], 0, 0, 0);
}

__global__ __launch_bounds__(512, 2) void attn_kernel(const bf16* __restrict__ Q,
                                                      const bf16* __restrict__ Kw,
                                                      const bf16* __restrict__ Vt,
                                                      bf16* __restrict__ Y) {
  __shared__ __align__(16) char lds[131072];
  const int tid = threadIdx.x;
  const int lane = tid & 63;
  const int wv = tid >> 6;
  const int g = lane >> 4, lr = lane & 15;
  const int bix = blockIdx.x;
  const int b = bix >> 6, h = (bix >> 2) & 15, tc = bix & 3;

  const bf16* Kh = Kw + (size_t)h * 512 * 64;
  const bf16* Vh = Vt + (size_t)h * 64 * 512;
  // stage K (64KB): rows 128B, pre-swizzled source
#pragma unroll
  for (int j = 0; j < 8; ++j) {
    int i = tid + j * 512;
    int r = i >> 3, c = i & 7;
    load_lds16((const char*)Kh + r * 128 + ((c * 16) ^ ((r & 7) << 4)), lds + (size_t)i * 16);
  }
  // stage V (64KB): rows 1024B, pre-swizzled source
#pragma unroll
  for (int j = 0; j < 8; ++j) {
    int i = tid + j * 512;
    int r = i >> 6, c = i & 63;
    load_lds16((const char*)Vh + r * 1024 + ((c * 16) ^ ((r & 7) << 4)),
               lds + 65536 + (size_t)i * 16);
  }

  // Q fragments straight from global (HBM, overlaps staging)
  const int tb = tc * 512 + wv * 64;
  const bf16* Qh = Q + ((size_t)(b * 16 + h) * 2048 + tb) * 64;
  bf16x8 qf[4][2];
#pragma unroll
  for (int s = 0; s < 4; ++s)
#pragma unroll
    for (int kk = 0; kk < 2; ++kk)
      qf[s][kk] = *(const bf16x8*)((const char*)Qh + (s * 16 + lr) * 128 + kk * 64 + g * 16);

  asm volatile("s_waitcnt vmcnt(0)" ::: "memory");
  __syncthreads();  // the only barrier

  f32x4 oacc[4][4] = {};  // [set][db]
  float psum[4] = {};

  Frags fA, fB;
  load_frags(fA, lds, 0, lr, g);
#pragma unroll 1
  for (int G = 0; G < 16; G += 2) {
    load_frags(fB, lds, G + 1, lr, g);
    compute_group(fA, qf, oacc, psum);
    if (G + 2 < 16) load_frags(fA, lds, G + 2, lr, g);
    compute_group(fB, qf, oacc, psum);
  }

  // finalize: sum over lane quarters, normalize, store
#pragma unroll
  for (int s = 0; s < 4; ++s) {
    float ssum = psum[s];
    ssum += __shfl_xor(ssum, 16);
    ssum += __shfl_xor(ssum, 32);
    float inv = 1.0f / ssum;
    int t = tb + s * 16 + lr;
    char* yrow = (char*)Y + ((size_t)(b * 2048 + t) * 1024 + h * 64) * 2;
#pragma unroll
    for (int db = 0; db < 4; ++db) {
      bf16x4 w;
#pragma unroll
      for (int j = 0; j < 4; ++j) w[j] = (bf16)(oacc[s][db][j] * inv);
      *(bf16x4*)(yrow + (db * 16 + g * 4) * 2) = w;
    }
  }
}

// ---------------- launch ----------------

extern "C" void kernel_launch(void* const* d_in, const int* in_sizes, int n_in, void* d_out,
                              int out_size, void* d_ws, size_t ws_size, hipStream_t stream) {
  const float* inpt = (const float*)d_in[0];
  const float* aux = (const float*)d_in[1];
  const float* q_w = (const float*)d_in[2];
  const float* q_b = (const float*)d_in[3];
  const float* kv_w = (const float*)d_in[4];
  const float* kv_b = (const float*)d_in[5];
  const float* out_w = (const float*)d_in[6];
  const float* out_b = (const float*)d_in[7];
  float* out = (float*)d_out;
  char* ws = (char*)d_ws;
  bf16* X = (bf16*)(ws + 0);              // 16MB: X bf16 ; reused as attn-out Y
  bf16* QZ = (bf16*)(ws + (16u << 20));   // 16MB: Q (B,H,T,D)
  bf16* qwb = (bf16*)(ws + (32u << 20));  // 2MB
  bf16* kvwb = (bf16*)(ws + (34u << 20)); // 4MB
  bf16* owb = (bf16*)(ws + (38u << 20));  // 2MB
  bf16* auxb = (bf16*)(ws + (40u << 20)); // 1MB
  bf16* Kws = (bf16*)(ws + (41u << 20));  // 1MB (H,L,D)
  bf16* Vtw = (bf16*)(ws + (42u << 20));  // 1MB (H,D,L) permuted slots

  prep<<<12800, 256, 0, stream>>>(q_w, qwb, kv_w, kvwb, out_w, owb, aux, auxb, inpt, X);
  gemm_qkv<<<576, 256, 0, stream>>>(X, qwb, q_b, QZ, auxb, kvwb, kv_b, Kws, Vtw);
  attn_kernel<<<256, 512, 0, stream>>>(QZ, Kws, Vtw, X /* Y reuses X */);
  gemm_outres<<<dim3(64, 8), 256, 0, stream>>>(X, owb, out_b, inpt, out);
}